// Round 1
// baseline (566.933 us; speedup 1.0000x reference)
//
#include <hip/hip_runtime.h>
#include <math.h>

#define DEVI __device__ __forceinline__

DEVI float silu_f(float x) { return x * (1.0f / (1.0f + __expf(-x))); }
DEVI float softplus_f(float x) {
  return x > 0.0f ? x + log1pf(__expf(-x)) : log1pf(__expf(x));
}

DEVI void load16(float* r, const float* __restrict__ p) {
  const float4* q = (const float4*)p;
  float4 a = q[0], b = q[1], c = q[2], d = q[3];
  r[0]=a.x; r[1]=a.y; r[2]=a.z; r[3]=a.w;
  r[4]=b.x; r[5]=b.y; r[6]=b.z; r[7]=b.w;
  r[8]=c.x; r[9]=c.y; r[10]=c.z; r[11]=c.w;
  r[12]=d.x; r[13]=d.y; r[14]=d.z; r[15]=d.w;
}
DEVI void store16(float* __restrict__ p, const float* r) {
  float4* q = (float4*)p;
  q[0] = make_float4(r[0],r[1],r[2],r[3]);
  q[1] = make_float4(r[4],r[5],r[6],r[7]);
  q[2] = make_float4(r[8],r[9],r[10],r[11]);
  q[3] = make_float4(r[12],r[13],r[14],r[15]);
}

// ---------------------------------------------------------------------------
// Generic tiled fp32 GEMM: C[m,n] = sum_k A[m,k] * W[n,k] (+ bias[n])
// A is batched (grid.z), optionally stored transposed (K x M per batch).
// EPI: 0 = split+transposed write (xz -> xcpre_t / z_t, both (bz,di,M))
//      1 = silu, row-major write
//      2 = LayerNorm (BN==Ntot), row-major write
//      3 = LayerNorm (BN==Ntot), transposed write (bz, Ntot, M)
// ---------------------------------------------------------------------------
constexpr int BM = 64;
constexpr int BK = 16;

template<int BN, bool ATRANS, int EPI>
__global__ __launch_bounds__(256) void gemm_kernel(
    const float* __restrict__ A, long sA,
    const float* __restrict__ W,
    const float* __restrict__ bias,
    int M, int Ntot, int K,
    float* __restrict__ out0, long sO0,
    float* __restrict__ out1, long sO1,
    const float* __restrict__ lnw, const float* __restrict__ lnb,
    int di)
{
  constexpr int TN = BN / 16;
  __shared__ float As[BK][BM];
  __shared__ float Ws[BK][BN];
  __shared__ float red[BM][17];

  const int tid = threadIdx.x;
  const int tx = tid & 15;   // n direction
  const int ty = tid >> 4;   // m direction
  const int m0 = blockIdx.x * BM;
  const int n0 = blockIdx.y * BN;
  const int bz = blockIdx.z;
  const float* __restrict__ Ab = A + (long)bz * sA;

  float acc[4][TN];
  #pragma unroll
  for (int i = 0; i < 4; ++i)
    #pragma unroll
    for (int j = 0; j < TN; ++j) acc[i][j] = 0.0f;

  for (int k0 = 0; k0 < K; k0 += BK) {
    if (ATRANS) {
      const int k = tid >> 4;
      const int m = (tid & 15) * 4;
      float4 v = *(const float4*)(Ab + (long)(k0 + k) * M + (m0 + m));
      *(float4*)(&As[k][m]) = v;
    } else {
      const int m = tid >> 2;
      const int kk = (tid & 3) * 4;
      float4 v = *(const float4*)(Ab + (long)(m0 + m) * K + (k0 + kk));
      As[kk+0][m] = v.x; As[kk+1][m] = v.y; As[kk+2][m] = v.z; As[kk+3][m] = v.w;
    }
    for (int q = tid; q < BN * BK / 4; q += 256) {
      const int n = q >> 2;
      const int kk = (q & 3) * 4;
      float4 v = *(const float4*)(W + (long)(n0 + n) * K + (k0 + kk));
      Ws[kk+0][n] = v.x; Ws[kk+1][n] = v.y; Ws[kk+2][n] = v.z; Ws[kk+3][n] = v.w;
    }
    __syncthreads();
    #pragma unroll
    for (int kk = 0; kk < BK; ++kk) {
      float4 av = *(const float4*)(&As[kk][ty * 4]);
      const float a0 = av.x, a1 = av.y, a2 = av.z, a3 = av.w;
      float b[TN];
      #pragma unroll
      for (int j4 = 0; j4 < TN / 4; ++j4) {
        float4 bv = *(const float4*)(&Ws[kk][tx * TN + j4 * 4]);
        b[j4*4+0] = bv.x; b[j4*4+1] = bv.y; b[j4*4+2] = bv.z; b[j4*4+3] = bv.w;
      }
      #pragma unroll
      for (int j = 0; j < TN; ++j) {
        acc[0][j] = fmaf(a0, b[j], acc[0][j]);
        acc[1][j] = fmaf(a1, b[j], acc[1][j]);
        acc[2][j] = fmaf(a2, b[j], acc[2][j]);
        acc[3][j] = fmaf(a3, b[j], acc[3][j]);
      }
    }
    __syncthreads();
  }

  if (bias != nullptr) {
    #pragma unroll
    for (int j = 0; j < TN; ++j) {
      const float bv = bias[n0 + tx * TN + j];
      #pragma unroll
      for (int i = 0; i < 4; ++i) acc[i][j] += bv;
    }
  }

  if constexpr (EPI == 0) {
    #pragma unroll
    for (int j = 0; j < TN; ++j) {
      const int n = n0 + tx * TN + j;
      float* dst = (n < di) ? (out0 + (long)bz * sO0 + (long)n * M)
                            : (out1 + (long)bz * sO1 + (long)(n - di) * M);
      *(float4*)(dst + m0 + ty * 4) =
          make_float4(acc[0][j], acc[1][j], acc[2][j], acc[3][j]);
    }
  } else if constexpr (EPI == 1) {
    #pragma unroll
    for (int i = 0; i < 4; ++i) {
      float* dst = out0 + ((long)bz * M + (m0 + ty * 4 + i)) * Ntot + n0 + tx * TN;
      #pragma unroll
      for (int j4 = 0; j4 < TN / 4; ++j4) {
        *(float4*)(dst + j4 * 4) = make_float4(
            silu_f(acc[i][j4*4+0]), silu_f(acc[i][j4*4+1]),
            silu_f(acc[i][j4*4+2]), silu_f(acc[i][j4*4+3]));
      }
    }
  } else {
    // LayerNorm over the full row (BN == Ntot, n0 == 0), two-pass.
    float mu[4], rstd[4];
    #pragma unroll
    for (int i = 0; i < 4; ++i) {
      float s = 0.0f;
      #pragma unroll
      for (int j = 0; j < TN; ++j) s += acc[i][j];
      red[ty * 4 + i][tx] = s;
    }
    __syncthreads();
    #pragma unroll
    for (int i = 0; i < 4; ++i) {
      float s = 0.0f;
      for (int t = 0; t < 16; ++t) s += red[ty * 4 + i][t];
      mu[i] = s * (1.0f / (float)Ntot);
    }
    __syncthreads();
    #pragma unroll
    for (int i = 0; i < 4; ++i) {
      float s = 0.0f;
      #pragma unroll
      for (int j = 0; j < TN; ++j) { float d = acc[i][j] - mu[i]; s = fmaf(d, d, s); }
      red[ty * 4 + i][tx] = s;
    }
    __syncthreads();
    #pragma unroll
    for (int i = 0; i < 4; ++i) {
      float s = 0.0f;
      for (int t = 0; t < 16; ++t) s += red[ty * 4 + i][t];
      rstd[i] = rsqrtf(s * (1.0f / (float)Ntot) + 1e-5f);
    }
    if constexpr (EPI == 2) {
      #pragma unroll
      for (int i = 0; i < 4; ++i) {
        float* dst = out0 + ((long)bz * M + (m0 + ty * 4 + i)) * Ntot + tx * TN;
        #pragma unroll
        for (int j4 = 0; j4 < TN / 4; ++j4) {
          float4 v;
          v.x = (acc[i][j4*4+0] - mu[i]) * rstd[i] * lnw[tx*TN+j4*4+0] + lnb[tx*TN+j4*4+0];
          v.y = (acc[i][j4*4+1] - mu[i]) * rstd[i] * lnw[tx*TN+j4*4+1] + lnb[tx*TN+j4*4+1];
          v.z = (acc[i][j4*4+2] - mu[i]) * rstd[i] * lnw[tx*TN+j4*4+2] + lnb[tx*TN+j4*4+2];
          v.w = (acc[i][j4*4+3] - mu[i]) * rstd[i] * lnw[tx*TN+j4*4+3] + lnb[tx*TN+j4*4+3];
          *(float4*)(dst + j4 * 4) = v;
        }
      }
    } else {  // EPI == 3: transposed write to (bz, Ntot, M)
      #pragma unroll
      for (int j = 0; j < TN; ++j) {
        const int n = tx * TN + j;
        const float g = lnw[n], bb = lnb[n];
        float* dst = out0 + (long)bz * sO0 + (long)n * M + m0 + ty * 4;
        *(float4*)dst = make_float4(
            (acc[0][j] - mu[0]) * rstd[0] * g + bb,
            (acc[1][j] - mu[1]) * rstd[1] * g + bb,
            (acc[2][j] - mu[2]) * rstd[2] * g + bb,
            (acc[3][j] - mu[3]) * rstd[3] * g + bb);
      }
    }
  }
}

// ---------------------------------------------------------------------------
// Fused: causal depthwise conv(4) + silu -> xc ; xdbl = xc @ wx^T (-> B,C) ;
// dt = softplus(xdbl[:r] @ wdt^T + bdt). All channel-major (b, di, L).
// One block = 16 sequence positions for all DI channels.
// ---------------------------------------------------------------------------
template<int DI, int R>
__global__ __launch_bounds__(256) void conv_proj_kernel(
    const float* __restrict__ xcpre_t,
    const float* __restrict__ cw, const float* __restrict__ cb,
    const float* __restrict__ wx, const float* __restrict__ wdt,
    const float* __restrict__ bdt,
    float* __restrict__ xc_t, float* __restrict__ dt_t,
    float* __restrict__ bc_t, int L)
{
  constexpr int LT = 16;
  constexpr int NP = R + 4;  // r + 2n, n=2
  __shared__ float xcs[DI][LT + 1];
  __shared__ float xds[NP][LT + 1];

  const int tid = threadIdx.x;
  const int l0 = blockIdx.x * LT;
  const int bz = blockIdx.y;

  if (tid < DI) {
    const int ch = tid;
    const long rowb = ((long)bz * DI + ch) * L;
    const float* __restrict__ src = xcpre_t + rowb + l0;
    float pre[LT + 3];
    if (l0 >= 3) {
      #pragma unroll
      for (int i = 0; i < LT + 3; ++i) pre[i] = src[i - 3];
    } else {
      #pragma unroll
      for (int i = 0; i < LT + 3; ++i) {
        const int l = l0 - 3 + i;
        pre[i] = (l >= 0) ? xcpre_t[rowb + l] : 0.0f;
      }
    }
    const float w0 = cw[ch*4+0], w1 = cw[ch*4+1], w2 = cw[ch*4+2], w3 = cw[ch*4+3];
    const float cbc = cb[ch];
    float v[LT];
    #pragma unroll
    for (int i = 0; i < LT; ++i) {
      float s = cbc;
      s = fmaf(pre[i+0], w0, s);
      s = fmaf(pre[i+1], w1, s);
      s = fmaf(pre[i+2], w2, s);
      s = fmaf(pre[i+3], w3, s);
      const float sv = silu_f(s);
      v[i] = sv;
      xcs[ch][i] = sv;
    }
    store16(xc_t + rowb + l0, v);
  }
  __syncthreads();

  for (int q = tid; q < NP * LT; q += 256) {
    const int j = q >> 4;
    const int i = q & 15;
    const float* __restrict__ wxr = wx + (long)j * DI;
    float s = 0.0f;
    #pragma unroll 8
    for (int ch = 0; ch < DI; ++ch) s = fmaf(xcs[ch][i], wxr[ch], s);
    xds[j][i] = s;
    if (j >= R) bc_t[((long)bz * 4 + (j - R)) * L + l0 + i] = s;
  }
  __syncthreads();

  if (tid < DI) {
    const int ch = tid;
    const long rowb = ((long)bz * DI + ch) * L;
    float wr[R];
    #pragma unroll
    for (int j = 0; j < R; ++j) wr[j] = wdt[ch * R + j];
    const float bv = bdt[ch];
    float v[LT];
    #pragma unroll
    for (int i = 0; i < LT; ++i) {
      float s = bv;
      #pragma unroll
      for (int j = 0; j < R; ++j) s = fmaf(xds[j][i], wr[j], s);
      v[i] = softplus_f(s);
    }
    store16(dt_t + rowb + l0, v);
  }
}

// ---------------------------------------------------------------------------
// Selective scan (n=2 states), block-parallel affine scan over L=4096.
// One block per (ch, b); 256 threads x 16 positions. h_t = a_t h_{t-1} + u_t,
// compose (P,Q): later∘earlier -> (Pe*Pl, Pl*Qe + Ql). h0 = 0 so h_in = Q_excl.
// Emits y = (h0*C0 + h1*C1 + dd*xc) * silu(z), channel-major.
// ---------------------------------------------------------------------------
__global__ __launch_bounds__(256) void scan_kernel(
    const float* __restrict__ dt_t, const float* __restrict__ xc_t,
    const float* __restrict__ z_t, const float* __restrict__ bc_t,
    const float* __restrict__ alog, const float* __restrict__ dd,
    float* __restrict__ y_t, int di, int L)
{
  const int ch = blockIdx.x;
  const int bz = blockIdx.y;
  const int tid = threadIdx.x;
  const int lane = tid & 63;
  const int w = tid >> 6;
  const long rowb = ((long)bz * di + ch) * L;
  const long bcb = (long)bz * 4 * L;
  const int l0 = tid * 16;

  __shared__ float wsP0[4], wsQ0[4], wsP1[4], wsQ1[4];

  const float A0 = -__expf(alog[ch * 2 + 0]);
  const float A1 = -__expf(alog[ch * 2 + 1]);
  const float ddc = dd[ch];

  float dtv[16], xcv[16], t0[16], t1[16];
  load16(dtv, dt_t + rowb + l0);
  load16(xcv, xc_t + rowb + l0);
  load16(t0, bc_t + bcb + l0);          // B0
  load16(t1, bc_t + bcb + L + l0);      // B1

  float a0[16], a1[16], u0[16], u1[16];
  float P0 = 1.0f, Q0 = 0.0f, P1 = 1.0f, Q1 = 0.0f;
  #pragma unroll
  for (int i = 0; i < 16; ++i) {
    const float dt = dtv[i];
    const float dx = dt * xcv[i];
    a0[i] = __expf(dt * A0);
    a1[i] = __expf(dt * A1);
    u0[i] = dx * t0[i];
    u1[i] = dx * t1[i];
    Q0 = fmaf(a0[i], Q0, u0[i]); P0 *= a0[i];
    Q1 = fmaf(a1[i], Q1, u1[i]); P1 *= a1[i];
  }

  // wave-level inclusive scan of affine (P,Q)
  #pragma unroll
  for (int off = 1; off < 64; off <<= 1) {
    const float pp0 = __shfl_up(P0, off);
    const float qq0 = __shfl_up(Q0, off);
    const float pp1 = __shfl_up(P1, off);
    const float qq1 = __shfl_up(Q1, off);
    if (lane >= off) {
      Q0 = fmaf(P0, qq0, Q0); P0 *= pp0;
      Q1 = fmaf(P1, qq1, Q1); P1 *= pp1;
    }
  }
  if (lane == 63) { wsP0[w] = P0; wsQ0[w] = Q0; wsP1[w] = P1; wsQ1[w] = Q1; }
  __syncthreads();
  float eQ0 = 0.0f, eQ1 = 0.0f;  // block prefix Q entering this wave (h0=0)
  for (int ww = 0; ww < w; ++ww) {
    eQ0 = fmaf(wsP0[ww], eQ0, wsQ0[ww]);
    eQ1 = fmaf(wsP1[ww], eQ1, wsQ1[ww]);
  }
  float pP0 = __shfl_up(P0, 1), pQ0 = __shfl_up(Q0, 1);
  float pP1 = __shfl_up(P1, 1), pQ1 = __shfl_up(Q1, 1);
  if (lane == 0) { pP0 = 1.0f; pQ0 = 0.0f; pP1 = 1.0f; pQ1 = 0.0f; }
  float h0 = fmaf(pP0, eQ0, pQ0);
  float h1 = fmaf(pP1, eQ1, pQ1);

  float c0[16], c1[16], zv[16], yv[16];
  load16(c0, bc_t + bcb + 2 * L + l0);  // C0
  load16(c1, bc_t + bcb + 3 * L + l0);  // C1
  load16(zv, z_t + rowb + l0);
  #pragma unroll
  for (int i = 0; i < 16; ++i) {
    h0 = fmaf(a0[i], h0, u0[i]);
    h1 = fmaf(a1[i], h1, u1[i]);
    const float y = fmaf(h0, c0[i], fmaf(h1, c1[i], ddc * xcv[i]));
    yv[i] = y * silu_f(zv[i]);
  }
  store16(y_t + rowb + l0, yv);
}

// ---------------------------------------------------------------------------
extern "C" void kernel_launch(void* const* d_in, const int* in_sizes, int n_in,
                              void* d_out, int out_size, void* d_ws, size_t ws_size,
                              hipStream_t stream)
{
  const float* x       = (const float*)d_in[0];
  const float* lin_w   = (const float*)d_in[1];
  const float* lin_b   = (const float*)d_in[2];
  const float* s1_win  = (const float*)d_in[3];
  const float* s1_bin  = (const float*)d_in[4];
  const float* s1_cw   = (const float*)d_in[5];
  const float* s1_cb   = (const float*)d_in[6];
  const float* s1_wx   = (const float*)d_in[7];
  const float* s1_wdt  = (const float*)d_in[8];
  const float* s1_bdt  = (const float*)d_in[9];
  const float* s1_alog = (const float*)d_in[10];
  const float* s1_dd   = (const float*)d_in[11];
  const float* s1_wout = (const float*)d_in[12];
  const float* s1_lnw  = (const float*)d_in[13];
  const float* s1_lnb  = (const float*)d_in[14];
  const float* s2_win  = (const float*)d_in[15];
  const float* s2_bin  = (const float*)d_in[16];
  const float* s2_cw   = (const float*)d_in[17];
  const float* s2_cb   = (const float*)d_in[18];
  const float* s2_wx   = (const float*)d_in[19];
  const float* s2_wdt  = (const float*)d_in[20];
  const float* s2_bdt  = (const float*)d_in[21];
  const float* s2_alog = (const float*)d_in[22];
  const float* s2_dd   = (const float*)d_in[23];
  const float* s2_wout = (const float*)d_in[24];
  const float* s2_lnw  = (const float*)d_in[25];
  const float* s2_lnb  = (const float*)d_in[26];
  float* out = (float*)d_out;

  const int B = 8, L = 4096;
  const long SLOT = 8L * 256 * 4096;  // 8.39M floats = 32 MB
  float* ws = (float*)d_ws;
  float* S0 = ws;
  float* S1 = ws + SLOT;
  float* S2 = ws + 2 * SLOT;
  float* S3 = ws + 3 * SLOT;
  float* S4 = ws + 4 * SLOT;
  float* SB = ws + 5 * SLOT;  // (B, 4, L) B0,B1,C0,C1

  // ---- stage 1 (d=di=128, r=8) ----
  // xz = x @ win^T + bin -> xcpre_t(S0), z_t(S1); x is (b, 128, 4096) = A^T
  gemm_kernel<128, true, 0><<<dim3(64, 2, B), 256, 0, stream>>>(
      x, 128L * 4096, s1_win, s1_bin, 4096, 256, 128,
      S0, 128L * 4096, S1, 128L * 4096, nullptr, nullptr, 128);
  // conv+silu -> xc_t(S2); x-proj -> B,C(SB); dt-proj -> dt_t(S3)
  conv_proj_kernel<128, 8><<<dim3(256, B), 256, 0, stream>>>(
      S0, s1_cw, s1_cb, s1_wx, s1_wdt, s1_bdt, S2, S3, SB, L);
  // scan -> y_t(S4)
  scan_kernel<<<dim3(128, B), 256, 0, stream>>>(
      S3, S2, S1, SB, s1_alog, s1_dd, S4, 128, L);
  // out-proj + LN -> act_mid(S0), row-major (b, L, 128)
  gemm_kernel<128, true, 2><<<dim3(64, 1, B), 256, 0, stream>>>(
      S4, 128L * 4096, s1_wout, nullptr, 4096, 128, 128,
      S0, 0, nullptr, 0, s1_lnw, s1_lnb, 0);
  // mid linear + silu -> act_lin(S1), row-major (b, L, 256)
  gemm_kernel<128, false, 1><<<dim3(64, 2, B), 256, 0, stream>>>(
      S0, 4096L * 128, lin_w, lin_b, 4096, 256, 128,
      S1, 0, nullptr, 0, nullptr, nullptr, 0);

  // ---- stage 2 (d=di=256, r=16) ----
  gemm_kernel<128, false, 0><<<dim3(64, 4, B), 256, 0, stream>>>(
      S1, 4096L * 256, s2_win, s2_bin, 4096, 512, 256,
      S2, 256L * 4096, S3, 256L * 4096, nullptr, nullptr, 256);
  conv_proj_kernel<256, 16><<<dim3(256, B), 256, 0, stream>>>(
      S2, s2_cw, s2_cb, s2_wx, s2_wdt, s2_bdt, S4, S0, SB, L);
  scan_kernel<<<dim3(256, B), 256, 0, stream>>>(
      S0, S4, S3, SB, s2_alog, s2_dd, S2, 256, L);
  // out-proj + LN, transposed write -> d_out (b, 256, 64, 64)
  gemm_kernel<256, true, 3><<<dim3(64, 1, B), 256, 0, stream>>>(
      S2, 256L * 4096, s2_wout, nullptr, 4096, 256, 256,
      out, 256L * 4096, nullptr, 0, s2_lnw, s2_lnb, 0);
}

// Round 2
// 402.992 us; speedup vs baseline: 1.4068x; 1.4068x over previous
//
#include <hip/hip_runtime.h>
#include <math.h>

#define DEVI __device__ __forceinline__

typedef unsigned int u32;
typedef unsigned short u16;
typedef __attribute__((ext_vector_type(8))) __bf16 bf16x8;
typedef __attribute__((ext_vector_type(8))) u16 u16x8;
typedef __attribute__((ext_vector_type(4))) float f32x4;

DEVI float silu_f(float x) { return x * (1.0f / (1.0f + __expf(-x))); }
DEVI float softplus_f(float x) {
  return x > 0.0f ? x + log1pf(__expf(-x)) : log1pf(__expf(x));
}

DEVI u32 bf16_rne(float f) {
  u32 u = __float_as_uint(f);
  return (u + 0x7fffu + ((u >> 16) & 1u)) >> 16;
}
// packed split: high 16 bits = bf16(f), low 16 bits = bf16(f - hi)
DEVI u32 pack_hl(float f) {
  u32 h = bf16_rne(f);
  float hf = __uint_as_float(h << 16);
  u32 l = bf16_rne(f - hf);
  return (h << 16) | l;
}

DEVI void load16(float* r, const float* __restrict__ p) {
  const float4* q = (const float4*)p;
  float4 a = q[0], b = q[1], c = q[2], d = q[3];
  r[0]=a.x; r[1]=a.y; r[2]=a.z; r[3]=a.w;
  r[4]=b.x; r[5]=b.y; r[6]=b.z; r[7]=b.w;
  r[8]=c.x; r[9]=c.y; r[10]=c.z; r[11]=c.w;
  r[12]=d.x; r[13]=d.y; r[14]=d.z; r[15]=d.w;
}
DEVI void store16(float* __restrict__ p, const float* r) {
  float4* q = (float4*)p;
  q[0] = make_float4(r[0],r[1],r[2],r[3]);
  q[1] = make_float4(r[4],r[5],r[6],r[7]);
  q[2] = make_float4(r[8],r[9],r[10],r[11]);
  q[3] = make_float4(r[12],r[13],r[14],r[15]);
}

// split 8 packed u32 into hi/lo bf16 chunks and store 16B each to LDS
DEVI void stage_chunk(u16* __restrict__ ph, u16* __restrict__ pl, uint4 a, uint4 b) {
  u16x8 h, l;
  h[0] = (u16)(a.x >> 16); l[0] = (u16)a.x;
  h[1] = (u16)(a.y >> 16); l[1] = (u16)a.y;
  h[2] = (u16)(a.z >> 16); l[2] = (u16)a.z;
  h[3] = (u16)(a.w >> 16); l[3] = (u16)a.w;
  h[4] = (u16)(b.x >> 16); l[4] = (u16)b.x;
  h[5] = (u16)(b.y >> 16); l[5] = (u16)b.y;
  h[6] = (u16)(b.z >> 16); l[6] = (u16)b.z;
  h[7] = (u16)(b.w >> 16); l[7] = (u16)b.w;
  *(u16x8*)ph = h; *(u16x8*)pl = l;
}

// ---------------------------------------------------------------------------
// Weight prep: convert 5 fp32 weight matrices to packed hi/lo bf16 (u32).
// ---------------------------------------------------------------------------
constexpr int WN1 = 32768, WNO1 = 16384, WNL = 32768, WN2 = 131072, WNO2 = 65536;
constexpr int WOFF1 = 0, WOFFO1 = 32768, WOFFL = 49152, WOFF2 = 81920, WOFFO2 = 212992;
constexpr int WTOT = 278528;

__global__ __launch_bounds__(256) void wprep_kernel(
    const float* __restrict__ w1, const float* __restrict__ wo1,
    const float* __restrict__ wl, const float* __restrict__ w2,
    const float* __restrict__ wo2, u32* __restrict__ dst)
{
  int i = blockIdx.x * 256 + threadIdx.x;
  float v;
  if (i < WOFFO1)       v = w1[i];
  else if (i < WOFFL)   v = wo1[i - WOFFO1];
  else if (i < WOFF2)   v = wl[i - WOFFL];
  else if (i < WOFFO2)  v = w2[i - WOFF2];
  else                  v = wo2[i - WOFFO2];
  dst[i] = pack_hl(v);
}

// ---------------------------------------------------------------------------
// Transpose: fp32 (b, C, L) -> packed u32 (b*L, C)
// ---------------------------------------------------------------------------
__global__ __launch_bounds__(256) void tpose_kernel(
    const float* __restrict__ in, u32* __restrict__ out, int C, int L)
{
  __shared__ float t[32][33];
  const int l0 = blockIdx.x * 32, c0 = blockIdx.y * 32, b = blockIdx.z;
  const int tx = threadIdx.x & 31, ty = threadIdx.x >> 5;
  const float* src = in + ((long)b * C + c0) * L + l0;
  #pragma unroll
  for (int r = 0; r < 32; r += 8) t[ty + r][tx] = src[(long)(ty + r) * L + tx];
  __syncthreads();
  u32* dst = out + ((long)b * L + l0) * C + c0;
  #pragma unroll
  for (int r = 0; r < 32; r += 8) dst[(long)(ty + r) * C + tx] = pack_hl(t[tx][ty + r]);
}

// ---------------------------------------------------------------------------
// MFMA GEMM (bf16x3 split): C[m,n] = sum_k A[m,k]*W[n,k] (+bias)
// A,W packed u32 hi/lo. Block 128x128, 4 waves (2x2), wave tile 64x64.
// EPI 0: split + transposed fp32 write (xz -> xcpre_t/z_t, (b,di,L))
// EPI 1: silu, packed u32 row-major write
// ---------------------------------------------------------------------------
template<int EPI>
__global__ __launch_bounds__(256) void mgemm_kernel(
    const u32* __restrict__ Ap, const u32* __restrict__ Wp,
    const float* __restrict__ bias, int M, int N, int K,
    float* __restrict__ out0, float* __restrict__ out1,
    u32* __restrict__ outp, int di, int L)
{
  __shared__ u16 Ah[128][40], Al[128][40], Bh[128][40], Bl[128][40];
  const int tid = threadIdx.x;
  const int wid = tid >> 6, lane = tid & 63;
  const int lm = lane & 15, lq = lane >> 4;
  const int m0 = blockIdx.y * 128, n0 = blockIdx.x * 128;
  const int wr = (wid >> 1) * 64, wn = (wid & 1) * 64;
  const int sr = tid >> 1;          // staging row 0..127
  const int sc = (tid & 1) * 2;     // staging chunk base (0 or 2)
  const int o0 = (((sc + 0) ^ (sr & 3)) * 8);
  const int o1 = (((sc + 1) ^ (sr & 3)) * 8);

  f32x4 acc[4][4];
  #pragma unroll
  for (int i = 0; i < 4; ++i)
    #pragma unroll
    for (int j = 0; j < 4; ++j)
      #pragma unroll
      for (int r = 0; r < 4; ++r) acc[i][j][r] = 0.0f;

  const u32* ga = Ap + (long)(m0 + sr) * K + sc * 8;
  const u32* gb = Wp + (long)(n0 + sr) * K + sc * 8;
  const int co = (lq ^ (lm & 3)) * 8;

  for (int k0 = 0; k0 < K; k0 += 32) {
    uint4 a0 = *(const uint4*)(ga + k0);
    uint4 a1 = *(const uint4*)(ga + k0 + 4);
    uint4 a2 = *(const uint4*)(ga + k0 + 8);
    uint4 a3 = *(const uint4*)(ga + k0 + 12);
    uint4 b0 = *(const uint4*)(gb + k0);
    uint4 b1 = *(const uint4*)(gb + k0 + 4);
    uint4 b2 = *(const uint4*)(gb + k0 + 8);
    uint4 b3 = *(const uint4*)(gb + k0 + 12);
    stage_chunk(&Ah[sr][o0], &Al[sr][o0], a0, a1);
    stage_chunk(&Ah[sr][o1], &Al[sr][o1], a2, a3);
    stage_chunk(&Bh[sr][o0], &Bl[sr][o0], b0, b1);
    stage_chunk(&Bh[sr][o1], &Bl[sr][o1], b2, b3);
    __syncthreads();

    bf16x8 fah[4], fal[4];
    #pragma unroll
    for (int i = 0; i < 4; ++i) {
      fah[i] = *(const bf16x8*)&Ah[wr + 16 * i + lm][co];
      fal[i] = *(const bf16x8*)&Al[wr + 16 * i + lm][co];
    }
    #pragma unroll
    for (int j = 0; j < 4; ++j) {
      bf16x8 fbh = *(const bf16x8*)&Bh[wn + 16 * j + lm][co];
      bf16x8 fbl = *(const bf16x8*)&Bl[wn + 16 * j + lm][co];
      #pragma unroll
      for (int i = 0; i < 4; ++i) {
        acc[i][j] = __builtin_amdgcn_mfma_f32_16x16x32_bf16(fah[i], fbh, acc[i][j], 0, 0, 0);
        acc[i][j] = __builtin_amdgcn_mfma_f32_16x16x32_bf16(fah[i], fbl, acc[i][j], 0, 0, 0);
        acc[i][j] = __builtin_amdgcn_mfma_f32_16x16x32_bf16(fal[i], fbh, acc[i][j], 0, 0, 0);
      }
    }
    __syncthreads();
  }

  if constexpr (EPI == 0) {
    const int b = m0 >> 12;
    const int lb = (m0 & 4095) + wr;
    #pragma unroll
    for (int j = 0; j < 4; ++j) {
      const int n = n0 + wn + 16 * j + lm;
      const float bv = bias[n];
      float* base = (n < di) ? out0 + ((long)b * di + n) * L
                             : out1 + ((long)b * di + (n - di)) * L;
      #pragma unroll
      for (int i = 0; i < 4; ++i) {
        const int l = lb + 16 * i + lq * 4;
        *(float4*)(base + l) = make_float4(acc[i][j][0] + bv, acc[i][j][1] + bv,
                                           acc[i][j][2] + bv, acc[i][j][3] + bv);
      }
    }
  } else {
    #pragma unroll
    for (int j = 0; j < 4; ++j) {
      const int n = n0 + wn + 16 * j + lm;
      const float bv = bias[n];
      #pragma unroll
      for (int i = 0; i < 4; ++i) {
        const long mg = m0 + wr + 16 * i + lq * 4;
        #pragma unroll
        for (int r = 0; r < 4; ++r)
          outp[(mg + r) * N + n] = pack_hl(silu_f(acc[i][j][r] + bv));
      }
    }
  }
}

// ---------------------------------------------------------------------------
// MFMA GEMM + fused LayerNorm over full width BN. Block 64xBN, 4 waves split
// along N, wave tile 64x(BN/4).
// EPI 2: packed u32 row-major write.  EPI 3: fp32 transposed write (b,BN,L).
// ---------------------------------------------------------------------------
template<int BN, int EPI>
__global__ __launch_bounds__(256) void lgemm_kernel(
    const u32* __restrict__ Ap, const u32* __restrict__ Wp,
    const float* __restrict__ lnw, const float* __restrict__ lnb,
    int M, int K, u32* __restrict__ outp, float* __restrict__ outf, int L)
{
  constexpr int NT = BN / 64;
  __shared__ u16 Ah[64][40], Al[64][40], Bh[BN][40], Bl[BN][40];
  __shared__ float red[4][64];
  __shared__ float muS[64], rsS[64];

  const int tid = threadIdx.x;
  const int wid = tid >> 6, lane = tid & 63;
  const int lm = lane & 15, lq = lane >> 4;
  const int m0 = blockIdx.x * 64;
  const int wn = wid * (BN / 4);
  const int sa_r = tid >> 2, sa_c = tid & 3;
  const int sa_o = ((sa_c ^ (sa_r & 3)) * 8);
  const int co = (lq ^ (lm & 3)) * 8;

  f32x4 acc[4][NT];
  #pragma unroll
  for (int i = 0; i < 4; ++i)
    #pragma unroll
    for (int j = 0; j < NT; ++j)
      #pragma unroll
      for (int r = 0; r < 4; ++r) acc[i][j][r] = 0.0f;

  const u32* ga = Ap + (long)(m0 + sa_r) * K + sa_c * 8;

  for (int k0 = 0; k0 < K; k0 += 32) {
    uint4 a0 = *(const uint4*)(ga + k0);
    uint4 a1 = *(const uint4*)(ga + k0 + 4);
    stage_chunk(&Ah[sa_r][sa_o], &Al[sa_r][sa_o], a0, a1);
    #pragma unroll
    for (int it = 0; it < NT; ++it) {
      const int idx = tid + it * 256;
      const int n = idx >> 2, c = idx & 3;
      const u32* gw = Wp + (long)n * K + k0 + c * 8;
      uint4 b0 = *(const uint4*)gw;
      uint4 b1 = *(const uint4*)(gw + 4);
      const int o = ((c ^ (n & 3)) * 8);
      stage_chunk(&Bh[n][o], &Bl[n][o], b0, b1);
    }
    __syncthreads();

    bf16x8 fah[4], fal[4];
    #pragma unroll
    for (int i = 0; i < 4; ++i) {
      fah[i] = *(const bf16x8*)&Ah[16 * i + lm][co];
      fal[i] = *(const bf16x8*)&Al[16 * i + lm][co];
    }
    #pragma unroll
    for (int j = 0; j < NT; ++j) {
      bf16x8 fbh = *(const bf16x8*)&Bh[wn + 16 * j + lm][co];
      bf16x8 fbl = *(const bf16x8*)&Bl[wn + 16 * j + lm][co];
      #pragma unroll
      for (int i = 0; i < 4; ++i) {
        acc[i][j] = __builtin_amdgcn_mfma_f32_16x16x32_bf16(fah[i], fbh, acc[i][j], 0, 0, 0);
        acc[i][j] = __builtin_amdgcn_mfma_f32_16x16x32_bf16(fah[i], fbl, acc[i][j], 0, 0, 0);
        acc[i][j] = __builtin_amdgcn_mfma_f32_16x16x32_bf16(fal[i], fbh, acc[i][j], 0, 0, 0);
      }
    }
    __syncthreads();
  }

  // ---- fused LayerNorm over BN ----
  float part[4][4];
  #pragma unroll
  for (int i = 0; i < 4; ++i)
    #pragma unroll
    for (int r = 0; r < 4; ++r) {
      float s = 0.0f;
      #pragma unroll
      for (int j = 0; j < NT; ++j) s += acc[i][j][r];
      part[i][r] = s;
    }
  #pragma unroll
  for (int off = 1; off < 16; off <<= 1)
    #pragma unroll
    for (int i = 0; i < 4; ++i)
      #pragma unroll
      for (int r = 0; r < 4; ++r) part[i][r] += __shfl_xor(part[i][r], off);
  if (lm == 0) {
    #pragma unroll
    for (int i = 0; i < 4; ++i)
      #pragma unroll
      for (int r = 0; r < 4; ++r) red[wid][16 * i + 4 * lq + r] = part[i][r];
  }
  __syncthreads();
  if (tid < 64)
    muS[tid] = (red[0][tid] + red[1][tid] + red[2][tid] + red[3][tid]) * (1.0f / BN);
  __syncthreads();
  float mu_l[4][4];
  #pragma unroll
  for (int i = 0; i < 4; ++i)
    #pragma unroll
    for (int r = 0; r < 4; ++r) mu_l[i][r] = muS[16 * i + 4 * lq + r];
  #pragma unroll
  for (int i = 0; i < 4; ++i)
    #pragma unroll
    for (int r = 0; r < 4; ++r) {
      float s = 0.0f;
      #pragma unroll
      for (int j = 0; j < NT; ++j) {
        float d = acc[i][j][r] - mu_l[i][r];
        s = fmaf(d, d, s);
      }
      part[i][r] = s;
    }
  #pragma unroll
  for (int off = 1; off < 16; off <<= 1)
    #pragma unroll
    for (int i = 0; i < 4; ++i)
      #pragma unroll
      for (int r = 0; r < 4; ++r) part[i][r] += __shfl_xor(part[i][r], off);
  if (lm == 0) {
    #pragma unroll
    for (int i = 0; i < 4; ++i)
      #pragma unroll
      for (int r = 0; r < 4; ++r) red[wid][16 * i + 4 * lq + r] = part[i][r];
  }
  __syncthreads();
  if (tid < 64)
    rsS[tid] = rsqrtf((red[0][tid] + red[1][tid] + red[2][tid] + red[3][tid]) * (1.0f / BN)
                      + 1e-5f);
  __syncthreads();
  float rs_l[4][4];
  #pragma unroll
  for (int i = 0; i < 4; ++i)
    #pragma unroll
    for (int r = 0; r < 4; ++r) rs_l[i][r] = rsS[16 * i + 4 * lq + r];

  if constexpr (EPI == 2) {
    #pragma unroll
    for (int j = 0; j < NT; ++j) {
      const int n = wn + 16 * j + lm;
      const float g = lnw[n], bb = lnb[n];
      #pragma unroll
      for (int i = 0; i < 4; ++i) {
        #pragma unroll
        for (int r = 0; r < 4; ++r) {
          const long mg = m0 + 16 * i + 4 * lq + r;
          outp[mg * BN + n] =
              pack_hl((acc[i][j][r] - mu_l[i][r]) * rs_l[i][r] * g + bb);
        }
      }
    }
  } else {
    const int b = m0 >> 12;
    const int lb = m0 & 4095;
    #pragma unroll
    for (int j = 0; j < NT; ++j) {
      const int n = wn + 16 * j + lm;
      const float g = lnw[n], bb = lnb[n];
      #pragma unroll
      for (int i = 0; i < 4; ++i) {
        const int l = lb + 16 * i + 4 * lq;
        float4 v;
        v.x = (acc[i][j][0] - mu_l[i][0]) * rs_l[i][0] * g + bb;
        v.y = (acc[i][j][1] - mu_l[i][1]) * rs_l[i][1] * g + bb;
        v.z = (acc[i][j][2] - mu_l[i][2]) * rs_l[i][2] * g + bb;
        v.w = (acc[i][j][3] - mu_l[i][3]) * rs_l[i][3] * g + bb;
        *(float4*)(outf + ((long)b * BN + n) * L + l) = v;
      }
    }
  }
}

// ---------------------------------------------------------------------------
// Fused: causal depthwise conv(4) + silu -> xc ; xdbl = xc @ wx^T (-> B,C) ;
// dt = softplus(xdbl[:r] @ wdt^T + bdt). All channel-major (b, di, L).
// ---------------------------------------------------------------------------
template<int DI, int R>
__global__ __launch_bounds__(256) void conv_proj_kernel(
    const float* __restrict__ xcpre_t,
    const float* __restrict__ cw, const float* __restrict__ cb,
    const float* __restrict__ wx, const float* __restrict__ wdt,
    const float* __restrict__ bdt,
    float* __restrict__ xc_t, float* __restrict__ dt_t,
    float* __restrict__ bc_t, int L)
{
  constexpr int LT = 16;
  constexpr int NP = R + 4;
  __shared__ float xcs[DI][LT + 1];
  __shared__ float xds[NP][LT + 1];

  const int tid = threadIdx.x;
  const int l0 = blockIdx.x * LT;
  const int bz = blockIdx.y;

  if (tid < DI) {
    const int ch = tid;
    const long rowb = ((long)bz * DI + ch) * L;
    const float* __restrict__ src = xcpre_t + rowb + l0;
    float pre[LT + 3];
    if (l0 >= 3) {
      #pragma unroll
      for (int i = 0; i < LT + 3; ++i) pre[i] = src[i - 3];
    } else {
      #pragma unroll
      for (int i = 0; i < LT + 3; ++i) {
        const int l = l0 - 3 + i;
        pre[i] = (l >= 0) ? xcpre_t[rowb + l] : 0.0f;
      }
    }
    const float w0 = cw[ch*4+0], w1 = cw[ch*4+1], w2 = cw[ch*4+2], w3 = cw[ch*4+3];
    const float cbc = cb[ch];
    float v[LT];
    #pragma unroll
    for (int i = 0; i < LT; ++i) {
      float s = cbc;
      s = fmaf(pre[i+0], w0, s);
      s = fmaf(pre[i+1], w1, s);
      s = fmaf(pre[i+2], w2, s);
      s = fmaf(pre[i+3], w3, s);
      const float sv = silu_f(s);
      v[i] = sv;
      xcs[ch][i] = sv;
    }
    store16(xc_t + rowb + l0, v);
  }
  __syncthreads();

  for (int q = tid; q < NP * LT; q += 256) {
    const int j = q >> 4;
    const int i = q & 15;
    const float* __restrict__ wxr = wx + (long)j * DI;
    float s = 0.0f;
    #pragma unroll 8
    for (int ch = 0; ch < DI; ++ch) s = fmaf(xcs[ch][i], wxr[ch], s);
    xds[j][i] = s;
    if (j >= R) bc_t[((long)bz * 4 + (j - R)) * L + l0 + i] = s;
  }
  __syncthreads();

  if (tid < DI) {
    const int ch = tid;
    const long rowb = ((long)bz * DI + ch) * L;
    float wr[R];
    #pragma unroll
    for (int j = 0; j < R; ++j) wr[j] = wdt[ch * R + j];
    const float bv = bdt[ch];
    float v[LT];
    #pragma unroll
    for (int i = 0; i < LT; ++i) {
      float s = bv;
      #pragma unroll
      for (int j = 0; j < R; ++j) s = fmaf(xds[j][i], wr[j], s);
      v[i] = softplus_f(s);
    }
    store16(dt_t + rowb + l0, v);
  }
}

// ---------------------------------------------------------------------------
// Selective scan (n=2 states), block-parallel affine scan over L.
// ---------------------------------------------------------------------------
__global__ __launch_bounds__(256) void scan_kernel(
    const float* __restrict__ dt_t, const float* __restrict__ xc_t,
    const float* __restrict__ z_t, const float* __restrict__ bc_t,
    const float* __restrict__ alog, const float* __restrict__ dd,
    float* __restrict__ y_t, int di, int L)
{
  const int ch = blockIdx.x;
  const int bz = blockIdx.y;
  const int tid = threadIdx.x;
  const int lane = tid & 63;
  const int w = tid >> 6;
  const long rowb = ((long)bz * di + ch) * L;
  const long bcb = (long)bz * 4 * L;
  const int l0 = tid * 16;

  __shared__ float wsP0[4], wsQ0[4], wsP1[4], wsQ1[4];

  const float A0 = -__expf(alog[ch * 2 + 0]);
  const float A1 = -__expf(alog[ch * 2 + 1]);
  const float ddc = dd[ch];

  float dtv[16], xcv[16], t0[16], t1[16];
  load16(dtv, dt_t + rowb + l0);
  load16(xcv, xc_t + rowb + l0);
  load16(t0, bc_t + bcb + l0);
  load16(t1, bc_t + bcb + L + l0);

  float a0[16], a1[16], u0[16], u1[16];
  float P0 = 1.0f, Q0 = 0.0f, P1 = 1.0f, Q1 = 0.0f;
  #pragma unroll
  for (int i = 0; i < 16; ++i) {
    const float dt = dtv[i];
    const float dx = dt * xcv[i];
    a0[i] = __expf(dt * A0);
    a1[i] = __expf(dt * A1);
    u0[i] = dx * t0[i];
    u1[i] = dx * t1[i];
    Q0 = fmaf(a0[i], Q0, u0[i]); P0 *= a0[i];
    Q1 = fmaf(a1[i], Q1, u1[i]); P1 *= a1[i];
  }

  #pragma unroll
  for (int off = 1; off < 64; off <<= 1) {
    const float pp0 = __shfl_up(P0, off);
    const float qq0 = __shfl_up(Q0, off);
    const float pp1 = __shfl_up(P1, off);
    const float qq1 = __shfl_up(Q1, off);
    if (lane >= off) {
      Q0 = fmaf(P0, qq0, Q0); P0 *= pp0;
      Q1 = fmaf(P1, qq1, Q1); P1 *= pp1;
    }
  }
  if (lane == 63) { wsP0[w] = P0; wsQ0[w] = Q0; wsP1[w] = P1; wsQ1[w] = Q1; }
  __syncthreads();
  float eQ0 = 0.0f, eQ1 = 0.0f;
  for (int ww = 0; ww < w; ++ww) {
    eQ0 = fmaf(wsP0[ww], eQ0, wsQ0[ww]);
    eQ1 = fmaf(wsP1[ww], eQ1, wsQ1[ww]);
  }
  float pP0 = __shfl_up(P0, 1), pQ0 = __shfl_up(Q0, 1);
  float pP1 = __shfl_up(P1, 1), pQ1 = __shfl_up(Q1, 1);
  if (lane == 0) { pP0 = 1.0f; pQ0 = 0.0f; pP1 = 1.0f; pQ1 = 0.0f; }
  float h0 = fmaf(pP0, eQ0, pQ0);
  float h1 = fmaf(pP1, eQ1, pQ1);

  float c0[16], c1[16], zv[16], yv[16];
  load16(c0, bc_t + bcb + 2 * L + l0);
  load16(c1, bc_t + bcb + 3 * L + l0);
  load16(zv, z_t + rowb + l0);
  #pragma unroll
  for (int i = 0; i < 16; ++i) {
    h0 = fmaf(a0[i], h0, u0[i]);
    h1 = fmaf(a1[i], h1, u1[i]);
    const float y = fmaf(h0, c0[i], fmaf(h1, c1[i], ddc * xcv[i]));
    yv[i] = y * silu_f(zv[i]);
  }
  store16(y_t + rowb + l0, yv);
}

// ---------------------------------------------------------------------------
extern "C" void kernel_launch(void* const* d_in, const int* in_sizes, int n_in,
                              void* d_out, int out_size, void* d_ws, size_t ws_size,
                              hipStream_t stream)
{
  const float* x       = (const float*)d_in[0];
  const float* lin_w   = (const float*)d_in[1];
  const float* lin_b   = (const float*)d_in[2];
  const float* s1_win  = (const float*)d_in[3];
  const float* s1_bin  = (const float*)d_in[4];
  const float* s1_cw   = (const float*)d_in[5];
  const float* s1_cb   = (const float*)d_in[6];
  const float* s1_wx   = (const float*)d_in[7];
  const float* s1_wdt  = (const float*)d_in[8];
  const float* s1_bdt  = (const float*)d_in[9];
  const float* s1_alog = (const float*)d_in[10];
  const float* s1_dd   = (const float*)d_in[11];
  const float* s1_wout = (const float*)d_in[12];
  const float* s1_lnw  = (const float*)d_in[13];
  const float* s1_lnb  = (const float*)d_in[14];
  const float* s2_win  = (const float*)d_in[15];
  const float* s2_bin  = (const float*)d_in[16];
  const float* s2_cw   = (const float*)d_in[17];
  const float* s2_cb   = (const float*)d_in[18];
  const float* s2_wx   = (const float*)d_in[19];
  const float* s2_wdt  = (const float*)d_in[20];
  const float* s2_bdt  = (const float*)d_in[21];
  const float* s2_alog = (const float*)d_in[22];
  const float* s2_dd   = (const float*)d_in[23];
  const float* s2_wout = (const float*)d_in[24];
  const float* s2_lnw  = (const float*)d_in[25];
  const float* s2_lnb  = (const float*)d_in[26];
  float* out = (float*)d_out;

  const int B = 8, L = 4096, M = 32768;
  const long SLOT = 8L * 256 * 4096;   // 8388608 elems = 32 MB
  const long HALF = SLOT / 2;          // 16 MB
  float* ws = (float*)d_ws;
  float* S0f = ws;             u32* S0u = (u32*)S0f;
  float* S1f = ws + SLOT;      u32* S1u = (u32*)S1f;
  float* S2f = ws + 2 * SLOT;  u32* S2u = (u32*)S2f;
  float* S3f = ws + 3 * SLOT;
  float* SBf = ws + 4 * SLOT;                       // (B,4,L) = 131072
  u32*   WP  = (u32*)(ws + 4 * SLOT + 131072);      // packed weights

  // 1. pack weights
  wprep_kernel<<<WTOT / 256, 256, 0, stream>>>(s1_win, s1_wout, lin_w, s2_win, s2_wout, WP);
  // 2. x (b,128,L) -> packed xT (M,128) @ S0u
  tpose_kernel<<<dim3(128, 4, B), 256, 0, stream>>>(x, S0u, 128, L);
  // 3. stage1 in-proj: -> xcpre1 @ S1f, z1 @ S1f+HALF
  mgemm_kernel<0><<<dim3(2, 256), 256, 0, stream>>>(
      S0u, WP + WOFF1, s1_bin, M, 256, 128, S1f, S1f + HALF, nullptr, 128, L);
  // 4. conv1 -> xc1 @ S2f, dt1 @ S2f+HALF, B/C @ SBf
  conv_proj_kernel<128, 8><<<dim3(256, B), 256, 0, stream>>>(
      S1f, s1_cw, s1_cb, s1_wx, s1_wdt, s1_bdt, S2f, S2f + HALF, SBf, L);
  // 5. scan1 -> y1 @ S0f
  scan_kernel<<<dim3(128, B), 256, 0, stream>>>(
      S2f + HALF, S2f, S1f + HALF, SBf, s1_alog, s1_dd, S0f, 128, L);
  // 6. y1 -> packed y1T @ S0u+HALF
  tpose_kernel<<<dim3(128, 4, B), 256, 0, stream>>>(S0f, S0u + HALF, 128, L);
  // 7. out-proj1 + LN -> act_mid packed @ S1u
  lgemm_kernel<128, 2><<<dim3(512), 256, 0, stream>>>(
      S0u + HALF, WP + WOFFO1, s1_lnw, s1_lnb, M, 128, S1u, nullptr, L);
  // 8. mid linear + silu -> act_lin packed @ S2u
  mgemm_kernel<1><<<dim3(2, 256), 256, 0, stream>>>(
      S1u, WP + WOFFL, lin_b, M, 256, 128, nullptr, nullptr, S2u, 0, L);
  // 9. stage2 in-proj: -> xcpre2 @ S0f, z2 @ S1f
  mgemm_kernel<0><<<dim3(4, 256), 256, 0, stream>>>(
      S2u, WP + WOFF2, s2_bin, M, 512, 256, S0f, S1f, nullptr, 256, L);
  // 10. conv2 -> xc2 @ S3f, dt2 @ S2f
  conv_proj_kernel<256, 16><<<dim3(256, B), 256, 0, stream>>>(
      S0f, s2_cw, s2_cb, s2_wx, s2_wdt, s2_bdt, S3f, S2f, SBf, L);
  // 11. scan2 -> y2 @ S0f
  scan_kernel<<<dim3(256, B), 256, 0, stream>>>(
      S2f, S3f, S1f, SBf, s2_alog, s2_dd, S0f, 256, L);
  // 12. y2 -> packed y2T @ S1u
  tpose_kernel<<<dim3(128, 8, B), 256, 0, stream>>>(S0f, S1u, 256, L);
  // 13. out-proj2 + LN -> d_out fp32 (b,256,64,64)
  lgemm_kernel<256, 3><<<dim3(512), 256, 0, stream>>>(
      S1u, WP + WOFFO2, s2_lnw, s2_lnb, M, 256, nullptr, out, L);
}